// Round 1
// baseline (899.627 us; speedup 1.0000x reference)
//
#include <hip/hip_runtime.h>
#include <math.h>

#define NT 256
#define T_SIZE 524288u
#define T_MASK 524287u
#define PR1 2654435761u
#define PR2 805459861u

__device__ __forceinline__ float sigmoidf_(float x) { return 1.0f / (1.0f + __expf(-x)); }
__device__ __forceinline__ float softplusf_(float x) { return fmaxf(x, 0.0f) + log1pf(__expf(-fabsf(x))); }

// acc[OUT] += in[j] * W[j][i], W row-major [K][OUT], fully unrolled, weights from LDS
template <int K, int OUT>
__device__ __forceinline__ void dense_acc(const float* in, const float* w, float* acc) {
#pragma unroll
  for (int j = 0; j < K; ++j) {
    float v = in[j];
    const float4* row = reinterpret_cast<const float4*>(w + j * OUT);
#pragma unroll
    for (int c = 0; c < OUT / 4; ++c) {
      float4 q = row[c];
      acc[4 * c + 0] += v * q.x;
      acc[4 * c + 1] += v * q.y;
      acc[4 * c + 2] += v * q.z;
      acc[4 * c + 3] += v * q.w;
    }
  }
}

extern "C" __global__ void __launch_bounds__(NT, 2) nerfw_fused(
    const float* __restrict__ x, const float* __restrict__ d,
    const int* __restrict__ aidx, const int* __restrict__ tridx,
    const float* __restrict__ tables,
    const float* __restrict__ emb_a, const float* __restrict__ emb_t,
    const float* __restrict__ Wd1, const float* __restrict__ bd1,
    const float* __restrict__ Wd2, const float* __restrict__ bd2,
    const float* __restrict__ Ws1, const float* __restrict__ bs1,
    const float* __restrict__ Ws2, const float* __restrict__ bs2,
    const float* __restrict__ Ws3, const float* __restrict__ bs3,
    const float* __restrict__ Wt1, const float* __restrict__ bt1,
    const float* __restrict__ Wt2, const float* __restrict__ bt2,
    const float* __restrict__ Wt3, const float* __restrict__ bt3,
    const float* __restrict__ Wtd, const float* __restrict__ btd,
    const float* __restrict__ Wtr, const float* __restrict__ btr,
    const float* __restrict__ Wtb, const float* __restrict__ btb,
    float* __restrict__ out, int Npts) {
  __shared__ __align__(16) float wl[10760];
  const int tid = threadIdx.x;
  const int n = blockIdx.x * NT + tid;
  const bool live = (n < Npts);
  const int nn = live ? n : 0;

  float x0 = x[3 * nn + 0], x1 = x[3 * nn + 1], x2 = x[3 * nn + 2];
  float xn0 = x0 * 0.25f, xn1 = x1 * 0.25f, xn2 = x2 * 0.25f;
  const bool mask = (fabsf(xn0) < 0.5f) && (fabsf(xn1) < 0.5f) && (fabsf(xn2) < 0.5f);
  xn0 += 0.5f; xn1 += 0.5f; xn2 += 0.5f;

  // ---------------- phase 0: density weights ----------------
  for (int i = tid; i < 2048; i += NT) wl[i] = Wd1[i];
  for (int i = tid; i < 1024; i += NT) wl[2048 + i] = Wd2[i];
  for (int i = tid; i < 64; i += NT) wl[3072 + i] = bd1[i];
  for (int i = tid; i < 16; i += NT) wl[3136 + i] = bd2[i];
  __syncthreads();

  // hash-grid features (indices always valid since T is a power of 2)
  float feats[32];
  const float2* tab2 = reinterpret_cast<const float2*>(tables);
  constexpr float NLV[16] = {16.f, 22.f, 30.f, 42.f, 58.f, 80.f, 111.f, 154.f,
                             213.f, 295.f, 407.f, 563.f, 777.f, 1074.f, 1483.f, 2048.f};
#pragma unroll
  for (int l = 0; l < 16; ++l) {
    const float sc = NLV[l];
    float xs0 = xn0 * sc, xs1 = xn1 * sc, xs2 = xn2 * sc;
    float f0 = floorf(xs0), f1 = floorf(xs1), f2 = floorf(xs2);
    float l0 = xs0 - f0, l1 = xs1 - f1, l2 = xs2 - f2;
    unsigned i0 = (unsigned)(int)f0, i1 = (unsigned)(int)f1, i2 = (unsigned)(int)f2;
    unsigned a0 = i0, a1 = i0 + 1u;
    unsigned b0 = i1 * PR1, b1 = (i1 + 1u) * PR1;
    unsigned c0 = i2 * PR2, c1 = (i2 + 1u) * PR2;
    const float2* tl = tab2 + (size_t)l * T_SIZE;
    float w0x = 1.f - l0, w1x = l0, w0y = 1.f - l1, w1y = l1, w0z = 1.f - l2, w1z = l2;
    float fa = 0.f, fb = 0.f;
    { float2 t = tl[(a0 ^ b0 ^ c0) & T_MASK]; float w = w0x * w0y * w0z; fa += w * t.x; fb += w * t.y; }
    { float2 t = tl[(a1 ^ b0 ^ c0) & T_MASK]; float w = w1x * w0y * w0z; fa += w * t.x; fb += w * t.y; }
    { float2 t = tl[(a0 ^ b1 ^ c0) & T_MASK]; float w = w0x * w1y * w0z; fa += w * t.x; fb += w * t.y; }
    { float2 t = tl[(a1 ^ b1 ^ c0) & T_MASK]; float w = w1x * w1y * w0z; fa += w * t.x; fb += w * t.y; }
    { float2 t = tl[(a0 ^ b0 ^ c1) & T_MASK]; float w = w0x * w0y * w1z; fa += w * t.x; fb += w * t.y; }
    { float2 t = tl[(a1 ^ b0 ^ c1) & T_MASK]; float w = w1x * w0y * w1z; fa += w * t.x; fb += w * t.y; }
    { float2 t = tl[(a0 ^ b1 ^ c1) & T_MASK]; float w = w0x * w1y * w1z; fa += w * t.x; fb += w * t.y; }
    { float2 t = tl[(a1 ^ b1 ^ c1) & T_MASK]; float w = w1x * w1y * w1z; fa += w * t.x; fb += w * t.y; }
    feats[2 * l] = fa;
    feats[2 * l + 1] = fb;
  }

  // density net: 32 -> 64 (relu) -> 16
  float hid[64];
#pragma unroll
  for (int i = 0; i < 64; ++i) hid[i] = wl[3072 + i];
  dense_acc<32, 64>(feats, wl + 0, hid);
#pragma unroll
  for (int i = 0; i < 64; ++i) hid[i] = fmaxf(hid[i], 0.f);
  float hv[16];
#pragma unroll
  for (int i = 0; i < 16; ++i) hv[i] = wl[3136 + i];
  dense_acc<64, 16>(hid, wl + 2048, hv);

  if (live) out[3 * (size_t)Npts + n] = mask ? __expf(hv[0]) : 0.f;

  __syncthreads();
  // ---------------- phase 1: static head weights ----------------
  for (int i = tid; i < 5824; i += NT) wl[i] = Ws1[i];
  for (int i = tid; i < 4096; i += NT) wl[5824 + i] = Ws2[i];
  for (int i = tid; i < 192; i += NT) wl[9920 + i] = Ws3[i];
  for (int i = tid; i < 64; i += NT) wl[10112 + i] = bs1[i];
  for (int i = tid; i < 64; i += NT) wl[10176 + i] = bs2[i];
  if (tid < 3) wl[10240 + tid] = bs3[tid];
  __syncthreads();

  float sa[64];
#pragma unroll
  for (int i = 0; i < 64; ++i) sa[i] = wl[10112 + i];
  dense_acc<16, 64>(hv, wl + 0, sa);
  {
    float denc[27];
    float d0 = d[3 * nn + 0], d1 = d[3 * nn + 1], d2 = d[3 * nn + 2];
    denc[0] = d0; denc[1] = d1; denc[2] = d2;
    float p = 1.f;
#pragma unroll
    for (int j = 0; j < 4; ++j) {
      denc[3 + 6 * j + 0] = __sinf(p * d0);
      denc[3 + 6 * j + 1] = __sinf(p * d1);
      denc[3 + 6 * j + 2] = __sinf(p * d2);
      denc[6 + 6 * j + 0] = __cosf(p * d0);
      denc[6 + 6 * j + 1] = __cosf(p * d1);
      denc[6 + 6 * j + 2] = __cosf(p * d2);
      p *= 2.f;
    }
    dense_acc<27, 64>(denc, wl + 16 * 64, sa);
  }
  {
    float ae[48];
    const float* ap = emb_a + (size_t)aidx[nn] * 48;
#pragma unroll
    for (int i = 0; i < 48; ++i) ae[i] = ap[i];
    dense_acc<48, 64>(ae, wl + 43 * 64, sa);
  }
#pragma unroll
  for (int i = 0; i < 64; ++i) sa[i] = fmaxf(sa[i], 0.f);
  float sb[64];
#pragma unroll
  for (int i = 0; i < 64; ++i) sb[i] = wl[10176 + i];
  dense_acc<64, 64>(sa, wl + 5824, sb);
#pragma unroll
  for (int i = 0; i < 64; ++i) sb[i] = fmaxf(sb[i], 0.f);
  float r0 = wl[10240], r1 = wl[10241], r2 = wl[10242];
#pragma unroll
  for (int j = 0; j < 64; ++j) {
    float v = sb[j];
    r0 += v * wl[9920 + 3 * j + 0];
    r1 += v * wl[9920 + 3 * j + 1];
    r2 += v * wl[9920 + 3 * j + 2];
  }
  r0 = sigmoidf_(r0); r1 = sigmoidf_(r1); r2 = sigmoidf_(r2);
  if (live) {
    out[3 * (size_t)n + 0] = mask ? r0 : 0.f;
    out[3 * (size_t)n + 1] = mask ? r1 : 0.f;
    out[3 * (size_t)n + 2] = mask ? r2 : 0.f;
  }

  __syncthreads();
  // ---------------- phase 2: transient head weights ----------------
  for (int i = tid; i < 2048; i += NT) wl[i] = Wt1[i];
  for (int i = tid; i < 4096; i += NT) wl[2048 + i] = Wt2[i];
  for (int i = tid; i < 4096; i += NT) wl[6144 + i] = Wt3[i];
  for (int i = tid; i < 64; i += NT) wl[10240 + i] = Wtd[i];
  for (int i = tid; i < 192; i += NT) wl[10304 + i] = Wtr[i];
  for (int i = tid; i < 64; i += NT) wl[10496 + i] = Wtb[i];
  for (int i = tid; i < 64; i += NT) wl[10560 + i] = bt1[i];
  for (int i = tid; i < 64; i += NT) wl[10624 + i] = bt2[i];
  for (int i = tid; i < 64; i += NT) wl[10688 + i] = bt3[i];
  if (tid == 0) { wl[10752] = btd[0]; wl[10756] = btb[0]; }
  if (tid < 3) wl[10753 + tid] = btr[tid];
  __syncthreads();

  float ta[64];
#pragma unroll
  for (int i = 0; i < 64; ++i) ta[i] = wl[10560 + i];
  dense_acc<16, 64>(hv, wl + 0, ta);
  {
    float te[16];
    const float* tp = emb_t + (size_t)tridx[nn] * 16;
#pragma unroll
    for (int i = 0; i < 16; ++i) te[i] = tp[i];
    dense_acc<16, 64>(te, wl + 16 * 64, ta);
  }
#pragma unroll
  for (int i = 0; i < 64; ++i) ta[i] = fmaxf(ta[i], 0.f);
  float tb_[64];
#pragma unroll
  for (int i = 0; i < 64; ++i) tb_[i] = wl[10624 + i];
  dense_acc<64, 64>(ta, wl + 2048, tb_);
#pragma unroll
  for (int i = 0; i < 64; ++i) tb_[i] = fmaxf(tb_[i], 0.f);
  float tc[64];
#pragma unroll
  for (int i = 0; i < 64; ++i) tc[i] = wl[10688 + i];
  dense_acc<64, 64>(tb_, wl + 6144, tc);
#pragma unroll
  for (int i = 0; i < 64; ++i) tc[i] = fmaxf(tc[i], 0.f);

  float hd = wl[10752], hr0 = wl[10753], hr1 = wl[10754], hr2 = wl[10755], hb = wl[10756];
#pragma unroll
  for (int j = 0; j < 64; ++j) {
    float v = tc[j];
    hd += v * wl[10240 + j];
    hr0 += v * wl[10304 + 3 * j + 0];
    hr1 += v * wl[10304 + 3 * j + 1];
    hr2 += v * wl[10304 + 3 * j + 2];
    hb += v * wl[10496 + j];
  }
  float tsig = softplusf_(hd);
  hr0 = sigmoidf_(hr0); hr1 = sigmoidf_(hr1); hr2 = sigmoidf_(hr2);
  float tbeta = softplusf_(hb) + 0.1f;
  if (live) {
    size_t N4 = (size_t)Npts * 4;
    out[N4 + 3 * (size_t)n + 0] = mask ? hr0 : 0.f;
    out[N4 + 3 * (size_t)n + 1] = mask ? hr1 : 0.f;
    out[N4 + 3 * (size_t)n + 2] = mask ? hr2 : 0.f;
    out[(size_t)Npts * 7 + n] = mask ? __expf(tsig) : 0.f;
    out[(size_t)Npts * 8 + n] = mask ? tbeta : 0.1f;
  }
}

extern "C" void kernel_launch(void* const* d_in, const int* in_sizes, int n_in,
                              void* d_out, int out_size, void* d_ws, size_t ws_size,
                              hipStream_t stream) {
  const int Npts = in_sizes[0] / 3;
  const float* x = (const float*)d_in[0];
  const float* d = (const float*)d_in[1];
  const int* aidx = (const int*)d_in[2];
  const int* tridx = (const int*)d_in[3];
  const float* tables = (const float*)d_in[4];
  const float* emb_a = (const float*)d_in[5];
  const float* emb_t = (const float*)d_in[6];
  const float* Wd1 = (const float*)d_in[7];
  const float* bd1 = (const float*)d_in[8];
  const float* Wd2 = (const float*)d_in[9];
  const float* bd2 = (const float*)d_in[10];
  const float* Ws1 = (const float*)d_in[11];
  const float* bs1 = (const float*)d_in[12];
  const float* Ws2 = (const float*)d_in[13];
  const float* bs2 = (const float*)d_in[14];
  const float* Ws3 = (const float*)d_in[15];
  const float* bs3 = (const float*)d_in[16];
  const float* Wt1 = (const float*)d_in[17];
  const float* bt1 = (const float*)d_in[18];
  const float* Wt2 = (const float*)d_in[19];
  const float* bt2 = (const float*)d_in[20];
  const float* Wt3 = (const float*)d_in[21];
  const float* bt3 = (const float*)d_in[22];
  const float* Wtd = (const float*)d_in[23];
  const float* btd = (const float*)d_in[24];
  const float* Wtr = (const float*)d_in[25];
  const float* btr = (const float*)d_in[26];
  const float* Wtb = (const float*)d_in[27];
  const float* btb = (const float*)d_in[28];
  float* out = (float*)d_out;

  int blocks = (Npts + NT - 1) / NT;
  hipLaunchKernelGGL(nerfw_fused, dim3(blocks), dim3(NT), 0, stream,
                     x, d, aidx, tridx, tables, emb_a, emb_t,
                     Wd1, bd1, Wd2, bd2, Ws1, bs1, Ws2, bs2, Ws3, bs3,
                     Wt1, bt1, Wt2, bt2, Wt3, bt3, Wtd, btd, Wtr, btr, Wtb, btb,
                     out, Npts);
}

// Round 2
// 696.057 us; speedup vs baseline: 1.2925x; 1.2925x over previous
//
#include <hip/hip_runtime.h>
#include <math.h>

#define NT 256
#define T_SIZE 524288u
#define T_MASK 524287u
#define PR1 2654435761u
#define PR2 805459861u

__device__ __forceinline__ float sigmoidf_(float x) { return 1.0f / (1.0f + __expf(-x)); }
__device__ __forceinline__ float softplusf_(float x) { return fmaxf(x, 0.0f) + log1pf(__expf(-fabsf(x))); }

// acc[i] += sum_j in[j] * w[j*STRIDE + i], i in [0,OUT); fully unrolled; w in LDS
template <int K, int OUT, int STRIDE>
__device__ __forceinline__ void dense_s(const float* in, const float* w, float* acc) {
#pragma unroll
  for (int j = 0; j < K; ++j) {
    float v = in[j];
    const float4* row = reinterpret_cast<const float4*>(w + j * STRIDE);
#pragma unroll
    for (int c = 0; c < OUT / 4; ++c) {
      float4 q = row[c];
      acc[4 * c + 0] += v * q.x;
      acc[4 * c + 1] += v * q.y;
      acc[4 * c + 2] += v * q.z;
      acc[4 * c + 3] += v * q.w;
    }
  }
}

__device__ __forceinline__ void stage(float* dst, const float* __restrict__ src, int cnt, int tid) {
  for (int i = tid; i < cnt; i += NT) dst[i] = src[i];
}

// ============ K0: hash-grid encode + density net -> hv[16] (ws), static_sigma ============
extern "C" __global__ void __launch_bounds__(NT, 4) k0_density(
    const float* __restrict__ x, const float* __restrict__ tables,
    const float* __restrict__ Wd1, const float* __restrict__ bd1,
    const float* __restrict__ Wd2, const float* __restrict__ bd2,
    float* __restrict__ hvws, float* __restrict__ out, int Npts) {
  __shared__ __align__(16) float wl[3152];
  const int tid = threadIdx.x;
  const int n = blockIdx.x * NT + tid;
  stage(wl, Wd1, 2048, tid);
  stage(wl + 2048, Wd2, 1024, tid);
  stage(wl + 3072, bd1, 64, tid);
  stage(wl + 3136, bd2, 16, tid);
  __syncthreads();
  if (n >= Npts) return;

  float x0 = x[3 * n + 0], x1 = x[3 * n + 1], x2 = x[3 * n + 2];
  float xn0 = x0 * 0.25f, xn1 = x1 * 0.25f, xn2 = x2 * 0.25f;
  const bool mask = (fabsf(xn0) < 0.5f) && (fabsf(xn1) < 0.5f) && (fabsf(xn2) < 0.5f);
  xn0 += 0.5f; xn1 += 0.5f; xn2 += 0.5f;

  float hid[64];
#pragma unroll
  for (int i = 0; i < 64; ++i) hid[i] = wl[3072 + i];

  const float2* tab2 = reinterpret_cast<const float2*>(tables);
  constexpr float NLV[16] = {16.f, 22.f, 30.f, 42.f, 58.f, 80.f, 111.f, 154.f,
                             213.f, 295.f, 407.f, 563.f, 777.f, 1074.f, 1483.f, 2048.f};
#pragma unroll
  for (int l = 0; l < 16; ++l) {
    const float sc = NLV[l];
    float xs0 = xn0 * sc, xs1 = xn1 * sc, xs2 = xn2 * sc;
    float f0 = floorf(xs0), f1 = floorf(xs1), f2 = floorf(xs2);
    float l0 = xs0 - f0, l1 = xs1 - f1, l2 = xs2 - f2;
    unsigned i0 = (unsigned)(int)f0, i1 = (unsigned)(int)f1, i2 = (unsigned)(int)f2;
    unsigned a0 = i0, a1 = i0 + 1u;
    unsigned b0 = i1 * PR1, b1 = (i1 + 1u) * PR1;
    unsigned c0 = i2 * PR2, c1 = (i2 + 1u) * PR2;
    const float2* tl = tab2 + (size_t)l * T_SIZE;
    float w0x = 1.f - l0, w1x = l0, w0y = 1.f - l1, w1y = l1, w0z = 1.f - l2, w1z = l2;
    float2 t0 = tl[(a0 ^ b0 ^ c0) & T_MASK];
    float2 t1 = tl[(a1 ^ b0 ^ c0) & T_MASK];
    float2 t2 = tl[(a0 ^ b1 ^ c0) & T_MASK];
    float2 t3 = tl[(a1 ^ b1 ^ c0) & T_MASK];
    float2 t4 = tl[(a0 ^ b0 ^ c1) & T_MASK];
    float2 t5 = tl[(a1 ^ b0 ^ c1) & T_MASK];
    float2 t6 = tl[(a0 ^ b1 ^ c1) & T_MASK];
    float2 t7 = tl[(a1 ^ b1 ^ c1) & T_MASK];
    float fv[2];
    float w000 = w0x * w0y * w0z, w100 = w1x * w0y * w0z;
    float w010 = w0x * w1y * w0z, w110 = w1x * w1y * w0z;
    float w001 = w0x * w0y * w1z, w101 = w1x * w0y * w1z;
    float w011 = w0x * w1y * w1z, w111 = w1x * w1y * w1z;
    fv[0] = w000 * t0.x + w100 * t1.x + w010 * t2.x + w110 * t3.x +
            w001 * t4.x + w101 * t5.x + w011 * t6.x + w111 * t7.x;
    fv[1] = w000 * t0.y + w100 * t1.y + w010 * t2.y + w110 * t3.y +
            w001 * t4.y + w101 * t5.y + w011 * t6.y + w111 * t7.y;
    dense_s<2, 64, 64>(fv, wl + 2 * l * 64, hid);
  }
#pragma unroll
  for (int i = 0; i < 64; ++i) hid[i] = fmaxf(hid[i], 0.f);
  float hv[16];
#pragma unroll
  for (int i = 0; i < 16; ++i) hv[i] = wl[3136 + i];
  dense_s<64, 16, 16>(hid, wl + 2048, hv);

  float4* hw = reinterpret_cast<float4*>(hvws + (size_t)n * 16);
  hw[0] = make_float4(hv[0], hv[1], hv[2], hv[3]);
  hw[1] = make_float4(hv[4], hv[5], hv[6], hv[7]);
  hw[2] = make_float4(hv[8], hv[9], hv[10], hv[11]);
  hw[3] = make_float4(hv[12], hv[13], hv[14], hv[15]);
  out[3 * (size_t)Npts + n] = mask ? __expf(hv[0]) : 0.f;
}

// ============ K1: static head ============
extern "C" __global__ void __launch_bounds__(NT, 4) k1_static(
    const float* __restrict__ x, const float* __restrict__ d,
    const int* __restrict__ aidx, const float* __restrict__ emb_a,
    const float* __restrict__ Ws1, const float* __restrict__ bs1,
    const float* __restrict__ Ws2, const float* __restrict__ bs2,
    const float* __restrict__ Ws3, const float* __restrict__ bs3,
    const float* __restrict__ hvws, float* __restrict__ out, int Npts) {
  __shared__ __align__(16) float wl[5888];
  const int tid = threadIdx.x;
  const int n = blockIdx.x * NT + tid;
  // stage A: Ws1 + bs1
  stage(wl, Ws1, 5824, tid);
  stage(wl + 5824, bs1, 64, tid);
  __syncthreads();
  const bool live = (n < Npts);
  const int nn = live ? n : 0;

  float xn0 = x[3 * nn + 0] * 0.25f, xn1 = x[3 * nn + 1] * 0.25f, xn2 = x[3 * nn + 2] * 0.25f;
  const bool mask = (fabsf(xn0) < 0.5f) && (fabsf(xn1) < 0.5f) && (fabsf(xn2) < 0.5f);

  float sa[64];
#pragma unroll
  for (int i = 0; i < 64; ++i) sa[i] = wl[5824 + i];
  {
    float hv[16];
    const float4* hw = reinterpret_cast<const float4*>(hvws + (size_t)nn * 16);
#pragma unroll
    for (int q = 0; q < 4; ++q) {
      float4 h4 = hw[q];
      hv[4 * q + 0] = h4.x; hv[4 * q + 1] = h4.y; hv[4 * q + 2] = h4.z; hv[4 * q + 3] = h4.w;
    }
    dense_s<16, 64, 64>(hv, wl + 0, sa);
  }
  {
    float dv[3];
    dv[0] = d[3 * nn + 0]; dv[1] = d[3 * nn + 1]; dv[2] = d[3 * nn + 2];
    dense_s<3, 64, 64>(dv, wl + 16 * 64, sa);
    float p = 1.f;
#pragma unroll
    for (int j = 0; j < 4; ++j) {
      float e6[6];
      e6[0] = __sinf(p * dv[0]); e6[1] = __sinf(p * dv[1]); e6[2] = __sinf(p * dv[2]);
      e6[3] = __cosf(p * dv[0]); e6[4] = __cosf(p * dv[1]); e6[5] = __cosf(p * dv[2]);
      dense_s<6, 64, 64>(e6, wl + (19 + 6 * j) * 64, sa);
      p *= 2.f;
    }
  }
  {
    const float4* ap = reinterpret_cast<const float4*>(emb_a + (size_t)aidx[nn] * 48);
#pragma unroll
    for (int j4 = 0; j4 < 12; ++j4) {
      float4 q = ap[j4];
      float a4[4] = {q.x, q.y, q.z, q.w};
      dense_s<4, 64, 64>(a4, wl + (43 + 4 * j4) * 64, sa);
    }
  }
#pragma unroll
  for (int i = 0; i < 64; ++i) sa[i] = fmaxf(sa[i], 0.f);

  __syncthreads();
  // stage B: Ws2 + Ws3 + bs2 + bs3
  stage(wl, Ws2, 4096, tid);
  stage(wl + 4096, Ws3, 192, tid);
  stage(wl + 4288, bs2, 64, tid);
  if (tid < 3) wl[4352 + tid] = bs3[tid];
  __syncthreads();

  float r0 = wl[4352], r1 = wl[4353], r2 = wl[4354];
#pragma unroll
  for (int c = 0; c < 4; ++c) {
    float sbc[16];
#pragma unroll
    for (int i = 0; i < 16; ++i) sbc[i] = wl[4288 + 16 * c + i];
    dense_s<64, 16, 64>(sa, wl + 16 * c, sbc);
#pragma unroll
    for (int i = 0; i < 16; ++i) {
      float v = fmaxf(sbc[i], 0.f);
      r0 += v * wl[4096 + 3 * (16 * c + i) + 0];
      r1 += v * wl[4096 + 3 * (16 * c + i) + 1];
      r2 += v * wl[4096 + 3 * (16 * c + i) + 2];
    }
  }
  if (live) {
    out[3 * (size_t)n + 0] = mask ? sigmoidf_(r0) : 0.f;
    out[3 * (size_t)n + 1] = mask ? sigmoidf_(r1) : 0.f;
    out[3 * (size_t)n + 2] = mask ? sigmoidf_(r2) : 0.f;
  }
}

// ============ K2: transient head ============
extern "C" __global__ void __launch_bounds__(NT, 3) k2_transient(
    const float* __restrict__ x, const int* __restrict__ tridx,
    const float* __restrict__ emb_t,
    const float* __restrict__ Wt1, const float* __restrict__ bt1,
    const float* __restrict__ Wt2, const float* __restrict__ bt2,
    const float* __restrict__ Wt3, const float* __restrict__ bt3,
    const float* __restrict__ Wtd, const float* __restrict__ btd,
    const float* __restrict__ Wtr, const float* __restrict__ btr,
    const float* __restrict__ Wtb, const float* __restrict__ btb,
    const float* __restrict__ hvws, float* __restrict__ out, int Npts) {
  __shared__ __align__(16) float wl[4488];
  const int tid = threadIdx.x;
  const int n = blockIdx.x * NT + tid;
  // stage A: Wt1 + bt1
  stage(wl, Wt1, 2048, tid);
  stage(wl + 2048, bt1, 64, tid);
  __syncthreads();
  const bool live = (n < Npts);
  const int nn = live ? n : 0;

  float xn0 = x[3 * nn + 0] * 0.25f, xn1 = x[3 * nn + 1] * 0.25f, xn2 = x[3 * nn + 2] * 0.25f;
  const bool mask = (fabsf(xn0) < 0.5f) && (fabsf(xn1) < 0.5f) && (fabsf(xn2) < 0.5f);

  float ta[64];
#pragma unroll
  for (int i = 0; i < 64; ++i) ta[i] = wl[2048 + i];
  {
    float hv[16];
    const float4* hw = reinterpret_cast<const float4*>(hvws + (size_t)nn * 16);
#pragma unroll
    for (int q = 0; q < 4; ++q) {
      float4 h4 = hw[q];
      hv[4 * q + 0] = h4.x; hv[4 * q + 1] = h4.y; hv[4 * q + 2] = h4.z; hv[4 * q + 3] = h4.w;
    }
    dense_s<16, 64, 64>(hv, wl + 0, ta);
  }
  {
    const float4* tp = reinterpret_cast<const float4*>(emb_t + (size_t)tridx[nn] * 16);
#pragma unroll
    for (int j4 = 0; j4 < 4; ++j4) {
      float4 q = tp[j4];
      float a4[4] = {q.x, q.y, q.z, q.w};
      dense_s<4, 64, 64>(a4, wl + (16 + 4 * j4) * 64, ta);
    }
  }
#pragma unroll
  for (int i = 0; i < 64; ++i) ta[i] = fmaxf(ta[i], 0.f);

  __syncthreads();
  // stage B: Wt2 + bt2
  stage(wl, Wt2, 4096, tid);
  stage(wl + 4096, bt2, 64, tid);
  __syncthreads();

  float tb_[64];
#pragma unroll
  for (int i = 0; i < 64; ++i) tb_[i] = wl[4096 + i];
  dense_s<64, 64, 64>(ta, wl + 0, tb_);
#pragma unroll
  for (int i = 0; i < 64; ++i) tb_[i] = fmaxf(tb_[i], 0.f);

  __syncthreads();
  // stage C: Wt3 + bt3 + heads
  stage(wl, Wt3, 4096, tid);
  stage(wl + 4096, bt3, 64, tid);
  stage(wl + 4160, Wtd, 64, tid);
  stage(wl + 4224, Wtr, 192, tid);
  stage(wl + 4416, Wtb, 64, tid);
  if (tid == 0) { wl[4480] = btd[0]; wl[4484] = btb[0]; }
  if (tid < 3) wl[4481 + tid] = btr[tid];
  __syncthreads();

  float hd = wl[4480], hr0 = wl[4481], hr1 = wl[4482], hr2 = wl[4483], hb = wl[4484];
#pragma unroll
  for (int c = 0; c < 4; ++c) {
    float tcc[16];
#pragma unroll
    for (int i = 0; i < 16; ++i) tcc[i] = wl[4096 + 16 * c + i];
    dense_s<64, 16, 64>(tb_, wl + 16 * c, tcc);
#pragma unroll
    for (int i = 0; i < 16; ++i) {
      float v = fmaxf(tcc[i], 0.f);
      int j = 16 * c + i;
      hd += v * wl[4160 + j];
      hr0 += v * wl[4224 + 3 * j + 0];
      hr1 += v * wl[4224 + 3 * j + 1];
      hr2 += v * wl[4224 + 3 * j + 2];
      hb += v * wl[4416 + j];
    }
  }
  if (live) {
    size_t N4 = (size_t)Npts * 4;
    out[N4 + 3 * (size_t)n + 0] = mask ? sigmoidf_(hr0) : 0.f;
    out[N4 + 3 * (size_t)n + 1] = mask ? sigmoidf_(hr1) : 0.f;
    out[N4 + 3 * (size_t)n + 2] = mask ? sigmoidf_(hr2) : 0.f;
    out[(size_t)Npts * 7 + n] = mask ? __expf(softplusf_(hd)) : 0.f;
    out[(size_t)Npts * 8 + n] = mask ? (softplusf_(hb) + 0.1f) : 0.1f;
  }
}

extern "C" void kernel_launch(void* const* d_in, const int* in_sizes, int n_in,
                              void* d_out, int out_size, void* d_ws, size_t ws_size,
                              hipStream_t stream) {
  const int Npts = in_sizes[0] / 3;
  const float* x = (const float*)d_in[0];
  const float* d = (const float*)d_in[1];
  const int* aidx = (const int*)d_in[2];
  const int* tridx = (const int*)d_in[3];
  const float* tables = (const float*)d_in[4];
  const float* emb_a = (const float*)d_in[5];
  const float* emb_t = (const float*)d_in[6];
  const float* Wd1 = (const float*)d_in[7];
  const float* bd1 = (const float*)d_in[8];
  const float* Wd2 = (const float*)d_in[9];
  const float* bd2 = (const float*)d_in[10];
  const float* Ws1 = (const float*)d_in[11];
  const float* bs1 = (const float*)d_in[12];
  const float* Ws2 = (const float*)d_in[13];
  const float* bs2 = (const float*)d_in[14];
  const float* Ws3 = (const float*)d_in[15];
  const float* bs3 = (const float*)d_in[16];
  const float* Wt1 = (const float*)d_in[17];
  const float* bt1 = (const float*)d_in[18];
  const float* Wt2 = (const float*)d_in[19];
  const float* bt2 = (const float*)d_in[20];
  const float* Wt3 = (const float*)d_in[21];
  const float* bt3 = (const float*)d_in[22];
  const float* Wtd = (const float*)d_in[23];
  const float* btd = (const float*)d_in[24];
  const float* Wtr = (const float*)d_in[25];
  const float* btr = (const float*)d_in[26];
  const float* Wtb = (const float*)d_in[27];
  const float* btb = (const float*)d_in[28];
  float* out = (float*)d_out;
  float* hvws = (float*)d_ws;  // 16 floats per point

  int blocks = (Npts + NT - 1) / NT;
  hipLaunchKernelGGL(k0_density, dim3(blocks), dim3(NT), 0, stream,
                     x, tables, Wd1, bd1, Wd2, bd2, hvws, out, Npts);
  hipLaunchKernelGGL(k1_static, dim3(blocks), dim3(NT), 0, stream,
                     x, d, aidx, emb_a, Ws1, bs1, Ws2, bs2, Ws3, bs3, hvws, out, Npts);
  hipLaunchKernelGGL(k2_transient, dim3(blocks), dim3(NT), 0, stream,
                     x, tridx, emb_t, Wt1, bt1, Wt2, bt2, Wt3, bt3,
                     Wtd, btd, Wtr, btr, Wtb, btb, hvws, out, Npts);
}